// Round 3
// baseline (1659.369 us; speedup 1.0000x reference)
//
#include <hip/hip_runtime.h>
#include <stdint.h>

#define E_TOT 500000
#define BM 64
#define NTHREADS 512
#define NBLOCKS 256
#define NT_TILES 7813   // ceil(E_TOT/BM)

typedef float f32x4 __attribute__((ext_vector_type(4)));
typedef short short8 __attribute__((ext_vector_type(8)));

// address-space casts for global_load_lds (low 32 bits of a generic LDS pointer = LDS offset)
#define AS1C(p) ((const __attribute__((address_space(1))) uint32_t*)(uintptr_t)(p))
#define AS3(p)  ((__attribute__((address_space(3))) uint32_t*)(uint32_t)(uintptr_t)(p))

__device__ __forceinline__ float b2f(ushort u) {
    union { uint32_t i; float f; } v; v.i = ((uint32_t)u) << 16; return v.f;
}
__device__ __forceinline__ ushort f2b(float f) {
    union { float f; uint32_t i; } v; v.f = f;
    uint32_t r = (v.i + 0x7FFFu + ((v.i >> 16) & 1u)) >> 16;
    return (ushort)r;
}
__device__ __forceinline__ float ldf(const void* p, int i, int f32m) {
    return f32m ? ((const float*)p)[i] : b2f(((const ushort*)p)[i]);
}

// ---- format detection: flags[0]=1 if float inputs are f32, flags[1]=1 if batch is int64 ----
__global__ void detect_fmt(const void* src, const void* batch, int* flags) {
    __shared__ int s_ok, s_nz;
    if (threadIdx.x == 0) { s_ok = 0; s_nz = 0; }
    __syncthreads();
    int t = threadIdx.x;
    if (t < 64) {
        float f = fabsf(b2f(((const ushort*)src)[2 * t]));
        if (f > 1e-3f && f < 1e2f) atomicAdd(&s_ok, 1);
    }
    int hv = ((const int*)batch)[2 * t + 1];
    if (hv != 0) atomicOr(&s_nz, 1);
    __syncthreads();
    if (t == 0) { flags[0] = (s_ok < 32) ? 1 : 0; flags[1] = (s_nz == 0) ? 1 : 0; }
}

// ---- prep: transpose weights -> bf16 [N][K], convert small params -> f32 ----
__global__ void prep(const int* __restrict__ flags,
                     const void* W1, const void* W2, const void* W3,
                     const void* Ww, const void* bw, const void* gw, const void* bew,
                     const void* b1, const void* g1, const void* be1,
                     const void* b2, const void* g2, const void* be2, const void* b3,
                     ushort* __restrict__ W1t, ushort* __restrict__ W2t,
                     ushort* __restrict__ W3t, float* __restrict__ params) {
    int f32m = flags[0];
    int id = blockIdx.x * 256 + threadIdx.x;
    if (id < 98304) {                     // W1 [384][256] -> W1t [256][384]
        int k = id >> 8, n = id & 255;
        W1t[n * 384 + k] = f2b(ldf(W1, id, f32m));
    } else if (id < 163840) {             // W2 [256][256] -> W2t [256][256]
        int t = id - 98304; int k = t >> 8, n = t & 255;
        W2t[n * 256 + k] = f2b(ldf(W2, t, f32m));
    } else if (id < 180224) {             // W3 [256][64] -> W3t [64][256]
        int t = id - 163840; int k = t >> 6, n = t & 63;
        W3t[n * 256 + k] = f2b(ldf(W3, t, f32m));
    } else if (id < 182464) {             // params -> f32
        int p = id - 180224;
        const void* sp; int off;
        if      (p < 256)  { sp = Ww;  off = p; }
        else if (p < 384)  { sp = bw;  off = p - 256; }
        else if (p < 512)  { sp = gw;  off = p - 384; }
        else if (p < 640)  { sp = bew; off = p - 512; }
        else if (p < 896)  { sp = b1;  off = p - 640; }
        else if (p < 1152) { sp = g1;  off = p - 896; }
        else if (p < 1408) { sp = be1; off = p - 1152; }
        else if (p < 1664) { sp = b2;  off = p - 1408; }
        else if (p < 1920) { sp = g2;  off = p - 1664; }
        else if (p < 2176) { sp = be2; off = p - 1920; }
        else               { sp = b3;  off = p - 2176; }
        params[p] = ldf(sp, off, f32m);
    }
}

// Round-3: persistent blocks. 256 blocks x 512 thr (1/CU, 8 waves, VGPR cap 256).
// W1/W2 column strips live in VGPRs (96+64/lane, loaded once); W3 in LDS (staged once).
// Each block grid-strides over ~31 row-tiles of 64. A staged 1 tile ahead into
// double-buffered LDS via global_load_lds(16B) with source-side inverse swizzle
// (phys granule = g ^ ((row&7)<<2): 2-way LDS reads = conflict-free).
// K-loops read only LDS + registers -> no global latency between MFMAs.
__global__ __launch_bounds__(NTHREADS, 2) void fused_edge_mlp(
    const void* __restrict__ srcv, const void* __restrict__ destv,
    const void* __restrict__ eav, const void* __restrict__ uv,
    const int* __restrict__ bp, const void* __restrict__ windv,
    const int* __restrict__ flags, const float* __restrict__ params,
    const ushort* __restrict__ W1t, const ushort* __restrict__ W2t, const ushort* __restrict__ W3t,
    float* __restrict__ outp)
{
    __shared__ __align__(16) ushort xA[2][BM * 256];   // 2 x 32KB: src|dest|ea|u, then h1/h2 in place
    __shared__ __align__(16) ushort xw[2][BM * 128];   // 2 x 16KB: winding MLP output
    __shared__ __align__(16) ushort w3lds[64 * 256];   // 32KB: W3 strip, persistent
    __shared__ float s_ww0[128], s_ww1[128], s_bw[128], s_gw[128], s_bew[128];
    __shared__ float s_b1[256], s_g1[256], s_be1[256];
    __shared__ float s_b2[256], s_g2[256], s_be2[256];
    __shared__ float s_b3[64];
    __shared__ int   s_uoff[2][BM];
    __shared__ float s_red1[BM * 8], s_red2[BM * 8];
    __shared__ float s_mu[BM], s_rs[BM];

    const int tid  = threadIdx.x;
    const int bid  = blockIdx.x;
    const int f32m = flags[0];
    const int i64m = flags[1];
    const int nt   = (NT_TILES - bid + NBLOCKS - 1) / NBLOCKS;

    const int lane = tid & 63;
    const int wav  = tid >> 6;
    const int q    = lane >> 4, n16 = lane & 15;
    const int colbase = wav * 32;
    const int koff = q * 8;

    // ---- stage small params ----
    if (tid < 128) {
        s_ww0[tid] = params[tid];        s_ww1[tid] = params[128 + tid];
        s_bw[tid]  = params[256 + tid];  s_gw[tid]  = params[384 + tid];
        s_bew[tid] = params[512 + tid];
    } else if (tid < 384) {
        int j = tid - 128;
        s_b1[j] = params[640 + j];  s_g1[j] = params[896 + j];  s_be1[j] = params[1152 + j];
        s_b2[j] = params[1408 + j]; s_g2[j] = params[1664 + j]; s_be2[j] = params[1920 + j];
    } else if (tid < 448) {
        s_b3[tid - 384] = params[2176 + tid - 384];
    }
    // uoff for tile 0 and tile 1
    if (tid < 64) {
        int gr = (bid + 0 * NBLOCKS) * BM + tid; if (gr >= E_TOT) gr = E_TOT - 1;
        s_uoff[0][tid] = (i64m ? bp[2 * gr] : bp[gr]) * 64;
    } else if (tid < 128 && nt > 1) {
        int r = tid - 64;
        int gr = (bid + 1 * NBLOCKS) * BM + r; if (gr >= E_TOT) gr = E_TOT - 1;
        s_uoff[1][r] = (i64m ? bp[2 * gr] : bp[gr]) * 64;
    }

    // ---- stage W3 -> LDS once (swizzled via source permutation; dest linear) ----
    #pragma unroll
    for (int i = 0; i < 4; ++i) {
        int G = wav * 256 + i * 64 + lane;          // granule 16B
        int row = G >> 5, p = G & 31;
        int lg = p ^ ((row & 7) << 2);              // logical granule for this phys slot
        __builtin_amdgcn_global_load_lds(AS1C(W3t + row * 256 + lg * 8),
                                         AS3(&w3lds[(size_t)(wav * 256 + i * 64) * 8]), 16, 0, 0);
    }

    // ---- W1/W2 strips -> registers (per-wave 32-col strip) ----
    short8 w1r[12][2];
    #pragma unroll
    for (int kc = 0; kc < 12; ++kc)
        #pragma unroll
        for (int ct = 0; ct < 2; ++ct)
            w1r[kc][ct] = *(const short8*)(W1t + (colbase + ct * 16 + n16) * 384 + kc * 32 + koff);
    short8 w2r[8][2];
    #pragma unroll
    for (int kc = 0; kc < 8; ++kc)
        #pragma unroll
        for (int ct = 0; ct < 2; ++ct)
            w2r[kc][ct] = *(const short8*)(W2t + (colbase + ct * 16 + n16) * 256 + kc * 32 + koff);

    __syncthreads();

    // ---- staging helpers ----
    auto stage_xA = [&](ushort* dst, int baseN, const int* uoffN) {
        #pragma unroll
        for (int i = 0; i < 4; ++i) {
            int G = wav * 256 + i * 64 + lane;
            int row = G >> 5, p = G & 31;
            int lg = p ^ ((row & 7) << 2);
            int tns = lg >> 3, coloff = (lg & 7) * 8;
            int gr = baseN + row; if (gr >= E_TOT) gr = E_TOT - 1;
            long eoff; const void* bsrc;
            if      (tns == 0) { bsrc = srcv;  eoff = (long)gr * 64 + coloff; }
            else if (tns == 1) { bsrc = destv; eoff = (long)gr * 64 + coloff; }
            else if (tns == 2) { bsrc = eav;   eoff = (long)gr * 64 + coloff; }
            else               { bsrc = uv;    eoff = (long)uoffN[row] + coloff; }
            if (!f32m) {
                __builtin_amdgcn_global_load_lds(AS1C((const ushort*)bsrc + eoff),
                    AS3(dst + (size_t)(wav * 256 + i * 64) * 8), 16, 0, 0);
            } else {
                const float* gp = (const float*)bsrc + eoff;
                float4 x0 = *(const float4*)gp, x1 = *(const float4*)(gp + 4);
                union { short8 v; ushort s[8]; } pk;
                pk.s[0] = f2b(x0.x); pk.s[1] = f2b(x0.y); pk.s[2] = f2b(x0.z); pk.s[3] = f2b(x0.w);
                pk.s[4] = f2b(x1.x); pk.s[5] = f2b(x1.y); pk.s[6] = f2b(x1.z); pk.s[7] = f2b(x1.w);
                *(short8*)(dst + (size_t)G * 8) = pk.v;
            }
        }
    };

    auto winding = [&](ushort* xwd, int baseN) {
        int r = tid >> 3, sub = tid & 7;            // 8 threads/row, 16 outputs each
        int gr = baseN + r; if (gr >= E_TOT) gr = E_TOT - 1;
        float w0, w1;
        if (f32m) { const float2 wp = ((const float2*)windv)[gr]; w0 = wp.x; w1 = wp.y; }
        else {
            uint32_t ww = ((const uint32_t*)windv)[gr];
            w0 = b2f((ushort)(ww & 0xFFFF)); w1 = b2f((ushort)(ww >> 16));
        }
        float s1 = 0.f, s2 = 0.f;
        float vv[16];
        #pragma unroll
        for (int j0 = 0; j0 < 16; ++j0) {
            int j = sub * 16 + j0;
            float t = fmaf(w0, s_ww0[j], fmaf(w1, s_ww1[j], s_bw[j]));
            vv[j0] = t; s1 += t; s2 += t * t;
        }
        s1 += __shfl_xor(s1, 1); s2 += __shfl_xor(s2, 1);
        s1 += __shfl_xor(s1, 2); s2 += __shfl_xor(s2, 2);
        s1 += __shfl_xor(s1, 4); s2 += __shfl_xor(s2, 4);
        float mu  = s1 * (1.f / 128.f);
        float var = s2 * (1.f / 128.f) - mu * mu;
        float rs  = rsqrtf(var + 1e-5f);
        #pragma unroll
        for (int gi = 0; gi < 2; ++gi) {
            union { short8 v; ushort s[8]; } pk;
            #pragma unroll
            for (int e = 0; e < 8; ++e) {
                int j = sub * 16 + gi * 8 + e;
                float t = (vv[gi * 8 + e] - mu) * rs * s_gw[j] + s_bew[j];
                pk.s[e] = f2b(fmaxf(t, 0.f));
            }
            int jg = sub * 2 + gi;
            *(short8*)&xwd[r * 128 + (jg ^ ((r & 3) << 2)) * 8] = pk.v;
        }
    };

    f32x4 acc[4][2];

    auto ln_epilogue = [&](ushort* xAc, const float* bias, const float* gamma, const float* beta) {
        #pragma unroll
        for (int rt = 0; rt < 4; ++rt) {
            #pragma unroll
            for (int i = 0; i < 4; ++i) {
                float sv = 0.f, sq = 0.f;
                #pragma unroll
                for (int ct = 0; ct < 2; ++ct) {
                    float t = acc[rt][ct][i] + bias[colbase + ct * 16 + n16];
                    acc[rt][ct][i] = t;                 // fold bias in place
                    sv += t; sq += t * t;
                }
                #pragma unroll
                for (int m = 1; m < 16; m <<= 1) {
                    sv += __shfl_xor(sv, m); sq += __shfl_xor(sq, m);
                }
                if (n16 == 0) {
                    int row = rt * 16 + q * 4 + i;
                    s_red1[row * 8 + wav] = sv; s_red2[row * 8 + wav] = sq;
                }
            }
        }
        __syncthreads();
        if (tid < BM) {
            float sv = 0.f, sq = 0.f;
            #pragma unroll
            for (int c = 0; c < 8; ++c) { sv += s_red1[tid * 8 + c]; sq += s_red2[tid * 8 + c]; }
            float mu  = sv * (1.f / 256.f);
            float var = sq * (1.f / 256.f) - mu * mu;
            s_mu[tid] = mu; s_rs[tid] = rsqrtf(var + 1e-5f);
        }
        __syncthreads();
        #pragma unroll
        for (int rt = 0; rt < 4; ++rt) {
            #pragma unroll
            for (int ct = 0; ct < 2; ++ct) {
                int col = colbase + ct * 16 + n16;
                float gg = gamma[col], be = beta[col];
                #pragma unroll
                for (int i = 0; i < 4; ++i) {
                    int row = rt * 16 + q * 4 + i;
                    float t = (acc[rt][ct][i] - s_mu[row]) * s_rs[row] * gg + be;
                    xAc[row * 256 + (((col >> 3) ^ ((row & 7) << 2)) << 3) + (col & 7)] = f2b(fmaxf(t, 0.f));
                }
            }
        }
        __syncthreads();
    };

    // ---- pipeline fill: stage tile 0 ----
    {
        int base0 = bid * BM;
        stage_xA(xA[0], base0, s_uoff[0]);
        winding(xw[0], base0);
    }

    // ---- main persistent loop ----
    for (int t = 0; t < nt; ++t) {
        const int cur = t & 1, nx = cur ^ 1;
        const int base = (bid + t * NBLOCKS) * BM;
        ushort* xAc = xA[cur];
        const ushort* xwc = xw[cur];

        __syncthreads();   // drains stage(t); guards xA[nx]/xw[nx] overwrite vs L3(t-1) reads

        if (t + 2 < nt && tid < 64) {
            int gr = (bid + (t + 2) * NBLOCKS) * BM + tid; if (gr >= E_TOT) gr = E_TOT - 1;
            s_uoff[cur][tid] = (i64m ? bp[2 * gr] : bp[gr]) * 64;
        }
        if (t + 1 < nt) {
            int baseN = (bid + (t + 1) * NBLOCKS) * BM;
            stage_xA(xA[nx], baseN, s_uoff[nx]);
            winding(xw[nx], baseN);
        }

        // ---- Layer 1: x[64,384] @ W1 (regs) -> acc ----
        #pragma unroll
        for (int a = 0; a < 4; ++a)
            #pragma unroll
            for (int b = 0; b < 2; ++b) acc[a][b] = (f32x4){0.f, 0.f, 0.f, 0.f};
        #pragma unroll
        for (int kc = 0; kc < 8; ++kc) {
            short8 afr[4];
            #pragma unroll
            for (int rt = 0; rt < 4; ++rt) {
                int row = rt * 16 + n16;
                afr[rt] = *(const short8*)&xAc[row * 256 + (((kc * 4 + q) ^ ((n16 & 7) << 2)) << 3)];
            }
            #pragma unroll
            for (int rt = 0; rt < 4; ++rt)
                #pragma unroll
                for (int ct = 0; ct < 2; ++ct)
                    acc[rt][ct] = __builtin_amdgcn_mfma_f32_16x16x32_bf16(afr[rt], w1r[kc][ct], acc[rt][ct], 0, 0, 0);
        }
        #pragma unroll
        for (int kc = 8; kc < 12; ++kc) {
            short8 afr[4];
            #pragma unroll
            for (int rt = 0; rt < 4; ++rt) {
                int row = rt * 16 + n16;
                afr[rt] = *(const short8*)&xwc[row * 128 + ((((kc - 8) * 4 + q) ^ ((n16 & 3) << 2)) << 3)];
            }
            #pragma unroll
            for (int rt = 0; rt < 4; ++rt)
                #pragma unroll
                for (int ct = 0; ct < 2; ++ct)
                    acc[rt][ct] = __builtin_amdgcn_mfma_f32_16x16x32_bf16(afr[rt], w1r[kc][ct], acc[rt][ct], 0, 0, 0);
        }
        ln_epilogue(xAc, s_b1, s_g1, s_be1);   // h1 -> xA[cur]

        // ---- Layer 2: h1[64,256] @ W2 (regs) ----
        #pragma unroll
        for (int a = 0; a < 4; ++a)
            #pragma unroll
            for (int b = 0; b < 2; ++b) acc[a][b] = (f32x4){0.f, 0.f, 0.f, 0.f};
        #pragma unroll
        for (int kc = 0; kc < 8; ++kc) {
            short8 afr[4];
            #pragma unroll
            for (int rt = 0; rt < 4; ++rt) {
                int row = rt * 16 + n16;
                afr[rt] = *(const short8*)&xAc[row * 256 + (((kc * 4 + q) ^ ((n16 & 7) << 2)) << 3)];
            }
            #pragma unroll
            for (int rt = 0; rt < 4; ++rt)
                #pragma unroll
                for (int ct = 0; ct < 2; ++ct)
                    acc[rt][ct] = __builtin_amdgcn_mfma_f32_16x16x32_bf16(afr[rt], w2r[kc][ct], acc[rt][ct], 0, 0, 0);
        }
        ln_epilogue(xAc, s_b2, s_g2, s_be2);   // h2 -> xA[cur]

        // ---- Layer 3: h2[64,256] @ W3 (LDS) -> out [64,64] ----
        f32x4 acc3[2];
        #pragma unroll
        for (int a = 0; a < 2; ++a) acc3[a] = (f32x4){0.f, 0.f, 0.f, 0.f};
        const int rhalf = wav >> 2, cg = wav & 3;
        #pragma unroll
        for (int kc = 0; kc < 8; ++kc) {
            int g = kc * 4 + q;
            short8 b3f = *(const short8*)&w3lds[(cg * 16 + n16) * 256 + ((g ^ ((n16 & 7) << 2)) << 3)];
            #pragma unroll
            for (int rt = 0; rt < 2; ++rt) {
                int row = rhalf * 32 + rt * 16 + n16;
                short8 a3 = *(const short8*)&xAc[row * 256 + ((g ^ ((n16 & 7) << 2)) << 3)];
                acc3[rt] = __builtin_amdgcn_mfma_f32_16x16x32_bf16(a3, b3f, acc3[rt], 0, 0, 0);
            }
        }
        #pragma unroll
        for (int rt = 0; rt < 2; ++rt) {
            int col = cg * 16 + n16;
            float bb = s_b3[col];
            #pragma unroll
            for (int i = 0; i < 4; ++i) {
                int row = rhalf * 32 + rt * 16 + q * 4 + i;
                int gr  = base + row;
                if (gr < E_TOT) outp[(long)gr * 64 + col] = acc3[rt][i] + bb;
            }
        }
    }
}

extern "C" void kernel_launch(void* const* d_in, const int* in_sizes, int n_in,
                              void* d_out, int out_size, void* d_ws, size_t ws_size,
                              hipStream_t stream) {
    int*    flags  = (int*)d_ws;
    float*  params = (float*)((char*)d_ws + 16);
    ushort* W1t    = (ushort*)((char*)d_ws + 9216);     // [256][384]
    ushort* W2t    = W1t + 98304;                        // [256][256]
    ushort* W3t    = W2t + 65536;                        // [64][256]

    detect_fmt<<<1, 256, 0, stream>>>(d_in[0], d_in[4], flags);
    prep<<<713, 256, 0, stream>>>(flags,
        d_in[10], d_in[14], d_in[18],
        d_in[6], d_in[7], d_in[8], d_in[9],
        d_in[11], d_in[12], d_in[13],
        d_in[15], d_in[16], d_in[17], d_in[19],
        W1t, W2t, W3t, params);

    fused_edge_mlp<<<NBLOCKS, NTHREADS, 0, stream>>>(
        d_in[0], d_in[1], d_in[2], d_in[3], (const int*)d_in[4], d_in[5],
        flags, params, W1t, W2t, W3t, (float*)d_out);
}